// Round 9
// baseline (542.033 us; speedup 1.0000x reference)
//
#include <hip/hip_runtime.h>
#include <hip/hip_bf16.h>
#include <math.h>

#define BB  64
#define CC  64
#define LL  720
#define LLP 736           // 720 padded to multiple of 32
#define DD  512
#define PP  336
#define P2C 168
#define HH  512
#define MM  (BB*CC)       // 4096

typedef _Float16 f16x8 __attribute__((ext_vector_type(8)));
typedef float    f32x4 __attribute__((ext_vector_type(4)));

#define GLDS16(g, l) __builtin_amdgcn_global_load_lds( \
    (const __attribute__((address_space(1))) void*)(g), \
    (__attribute__((address_space(3))) void*)(l), 16, 0, 0)

// Fast tanh: one v_exp + v_rcp; inf-safe (|x| large -> e=inf -> 2/inf=0 -> 1).
__device__ __forceinline__ float ftanh(float x) {
  const float ax = fabsf(x);
  const float e  = __expf(2.f * ax);
  const float t  = 1.f - 2.f / (e + 1.f);
  return copysignf(t, x);
}

// ---------------------------------------------------------------------------
// Batched weight convert: fp32 W[K][N] -> fp16 hi/lo planes Wt[N][Kpad]
struct WDesc { const float* src; _Float16* dstHi; _Float16* dstLo;
               int K, N, Kpad, tbase, tilesN; };
struct WTab  { WDesc d[12]; };

__global__ __launch_bounds__(256) void k_convert(WTab tab) {
  __shared__ float tile[16][17];
  const int bid = blockIdx.x;
  int wi = 0;
#pragma unroll
  for (int i = 1; i < 12; ++i) if (bid >= tab.d[i].tbase) wi = i;
  const WDesc d = tab.d[wi];
  const int lt = bid - d.tbase;
  const int tk = lt / d.tilesN, tn = lt % d.tilesN;
  const int k0 = tk * 16, n0 = tn * 16;
  const int tx = threadIdx.x & 15, ty = threadIdx.x >> 4;
  float v = 0.f;
  if (n0 + tx < d.N) v = d.src[(size_t)(k0 + ty) * d.N + n0 + tx];
  tile[ty][tx] = v;
  __syncthreads();
  if (n0 + ty < d.N) {
    const float w = tile[tx][ty];
    const _Float16 h = (_Float16)w;
    const _Float16 l = (_Float16)(w - (float)h);
    const size_t base = (size_t)(n0 + ty) * d.Kpad;
    d.dstHi[base + k0 + tx] = h;
    d.dstLo[base + k0 + tx] = l;
    if (d.Kpad != d.K && k0 + 16 == d.K) {
      d.dstHi[base + d.K + tx] = (_Float16)0.f;
      d.dstLo[base + d.K + tx] = (_Float16)0.f;
    }
  }
}

// ---------------------------------------------------------------------------
// x_bsd [B][L][C] -> x hi/lo [M][736] (pad cols zeroed)
__global__ __launch_bounds__(256) void k_xpose(const float* __restrict__ xbsd,
                                               _Float16* __restrict__ xhi,
                                               _Float16* __restrict__ xlo) {
  __shared__ float tile[16][17];
  const int b = blockIdx.z, l0 = blockIdx.x * 16, c0 = blockIdx.y * 16;
  const int tx = threadIdx.x, ty = threadIdx.y;
  tile[ty][tx] = xbsd[(size_t)b * LL * CC + (size_t)(l0 + ty) * CC + c0 + tx];
  __syncthreads();
  const float v = tile[tx][ty];
  const _Float16 h = (_Float16)v;
  const _Float16 l = (_Float16)(v - (float)h);
  const size_t m = (size_t)b * CC + c0 + ty;
  xhi[m * LLP + l0 + tx] = h;
  xlo[m * LLP + l0 + tx] = l;
  if (l0 == 704) {
    xhi[m * LLP + 720 + tx] = (_Float16)0.f;
    xlo[m * LLP + 720 + tx] = (_Float16)0.f;
  }
}

// ---------------------------------------------------------------------------
// Split-3 MFMA GEMM v12: BM=64, BN=64, BK=32; 256 threads = 4 waves (2x2:
// wave owns 32 rows x 32 cols, dual S+T). Keeps v11's XCD swizzle + ftanh.
// v12 change: ZERO-BARRIER per-wave-private pipeline. Rounds 2-8 showed all
// barrier-coupled schedules cluster at 43-46 µs/x-dispatch with MfmaUtil 16%,
// Occupancy 14-24% (~1-2 resident blocks), all pipes <30% -> lockstep convoy.
// Now: NO __syncthreads in the K-loop. A-fragments are per-lane contiguous
// 16B in global (v10-verified) -> direct global->VGPR, register-double-
// buffered. B staged into a PER-WAVE private 8 KB LDS region (DMA dest
// linear, global-side XOR swizzle as before). Each wave self-paces:
//   vmcnt(0)          (own B-DMA(k) + A(k) regs landed; covered by MFMA(k-1))
//   8 ds_reads of B(k)
//   lgkmcnt(0)+sched_barrier   (frags in regs -> own buffer safe to re-stage)
//   stageB(k+1) + A-prefetch(k+1)
//   24 MFMA (k)
// No inter-wave hazards exist at all. LDS: dual 32 KB, single 16 KB.
// Cost: A/B staged 2x per block (sibling-wave dup; L1/L2 absorb).
// EPI: 0 = affine (dual s/t; out = Vin*vscale*exp(tanh(S)) + T)
//      1 = gelu  (single; hi/lo out)
//      2 = raw   (single; transposed fp32 out)
template<int EPI, bool DUAL, bool VIN16, bool OUT_T>
__global__ __launch_bounds__(256)
void k_gemm(const _Float16* Ahi, const _Float16* Alo, int lda,
            const _Float16* Whi, const _Float16* Wlo, int ldw,
            const float* Vin32, const _Float16* VinHi,
            const _Float16* VinLo, int ldv, float vscale,
            float* outT32,
            _Float16* outHi, _Float16* outLo, int ldo,
            int Kp, int Nv) {
  constexpr int NBW  = DUAL ? 64 : 32;      // B rows per wave (S [+T])
  constexpr int WBUF = NBW * 32;            // halves per plane per wave
  constexpr int NCH  = 2 * (NBW / 16);      // DMA chunks/wave: dual 8, single 4
  __shared__ _Float16 smem[4 * 2 * WBUF];   // 4 waves x 2 planes (32 / 16 KB)

  // XCD-aware bijective swizzle (nwg % 8 == 0 for every grid used here),
  // decoded m-major so each XCD holds a contiguous run of m-panels.
  const int gx  = gridDim.x;
  const int nwg = gx * gridDim.y;
  const int id  = blockIdx.y * gx + blockIdx.x;
  const int nid = (id & 7) * (nwg >> 3) + (id >> 3);
  const int m0 = (nid / gx) * 64;
  const int n0 = (nid % gx) * 64;

  const int tid = threadIdx.x;
  const int w = tid >> 6, lane = tid & 63, q = lane >> 4, r = lane & 15;
  const int wr = (w & 1) * 32, wc = (w >> 1) * 32;
  const int lr = lane >> 2, ls = lane & 3;  // DMA lane decode

  _Float16* wbase = smem + w * (2 * WBUF);  // this wave's private region

  f32x4 accS[2][2] = {};
  f32x4 accT[2][2] = {};

  // ---- issue this wave's B DMA for k-tile kc into its private region
  auto stageB = [&](int kc) {
    const int k0 = kc << 5;
#pragma unroll
    for (int cc = 0; cc < NCH; ++cc) {
      const int pl   = (cc >= NCH / 2) ? 1 : 0;
      const int rb   = (cc % (NCH / 2)) * 16;
      const int lrow = rb + lr;
      const int ss   = ls ^ ((lrow >> 1) & 3);
      const int wrow = (lrow < 32) ? (n0 + wc + lrow)
                                   : (Nv + n0 + wc + (lrow - 32));
      const _Float16* g = (pl ? Wlo : Whi) + (size_t)wrow * ldw + k0 + ss * 8;
      GLDS16(g, wbase + pl * WBUF + rb * 32);
    }
  };

  // ---- A-fragment base pointers (lane-fixed; step offset = kc*32)
  const _Float16* aH0 = Ahi + (size_t)(m0 + wr + r)      * lda + q * 8;
  const _Float16* aH1 = Ahi + (size_t)(m0 + wr + 16 + r) * lda + q * 8;
  const _Float16* aL0 = Alo + (size_t)(m0 + wr + r)      * lda + q * 8;
  const _Float16* aL1 = Alo + (size_t)(m0 + wr + 16 + r) * lda + q * 8;

  const int nk = Kp >> 5;
  stageB(0);
  f16x8 c0h = *(const f16x8*)(aH0);
  f16x8 c1h = *(const f16x8*)(aH1);
  f16x8 c0l = *(const f16x8*)(aL0);
  f16x8 c1l = *(const f16x8*)(aL1);
  f16x8 p0h = c0h, p1h = c1h, p0l = c0l, p1l = c1l;

  for (int kc = 0; kc < nk; ++kc) {
    // Own B-DMA(kc) and A(kc) prefetch landed (issued before MFMA(kc-1)).
    asm volatile("s_waitcnt vmcnt(0)" ::: "memory");
    __builtin_amdgcn_sched_barrier(0);

    // Read this step's B fragments from the private region.
    f16x8 bhS[2], blS[2], bhT[2], blT[2];
#pragma unroll
    for (int ct = 0; ct < 2; ++ct) {
      const int rs = ct * 16 + r;                 // S local row
      const int tb = (q ^ ((rs >> 1) & 3)) * 8;
      bhS[ct] = *(const f16x8*)(wbase + rs * 32 + tb);
      blS[ct] = *(const f16x8*)(wbase + WBUF + rs * 32 + tb);
      if (DUAL) {
        const int rt2 = 32 + ct * 16 + r;         // T local row
        const int tt = (q ^ ((rt2 >> 1) & 3)) * 8;
        bhT[ct] = *(const f16x8*)(wbase + rt2 * 32 + tt);
        blT[ct] = *(const f16x8*)(wbase + WBUF + rt2 * 32 + tt);
      }
    }
    // Fragments complete -> own buffer free; then prefetch next tile.
    asm volatile("s_waitcnt lgkmcnt(0)" ::: "memory");
    __builtin_amdgcn_sched_barrier(0);
    if (kc + 1 < nk) {                            // wave-uniform branch
      stageB(kc + 1);
      const int ko = (kc + 1) << 5;
      p0h = *(const f16x8*)(aH0 + ko);
      p1h = *(const f16x8*)(aH1 + ko);
      p0l = *(const f16x8*)(aL0 + ko);
      p1l = *(const f16x8*)(aL1 + ko);
    }

#pragma unroll
    for (int ct = 0; ct < 2; ++ct) {
      accS[0][ct] = __builtin_amdgcn_mfma_f32_16x16x32_f16(c0h, bhS[ct], accS[0][ct], 0, 0, 0);
      accS[0][ct] = __builtin_amdgcn_mfma_f32_16x16x32_f16(c0l, bhS[ct], accS[0][ct], 0, 0, 0);
      accS[0][ct] = __builtin_amdgcn_mfma_f32_16x16x32_f16(c0h, blS[ct], accS[0][ct], 0, 0, 0);
      accS[1][ct] = __builtin_amdgcn_mfma_f32_16x16x32_f16(c1h, bhS[ct], accS[1][ct], 0, 0, 0);
      accS[1][ct] = __builtin_amdgcn_mfma_f32_16x16x32_f16(c1l, bhS[ct], accS[1][ct], 0, 0, 0);
      accS[1][ct] = __builtin_amdgcn_mfma_f32_16x16x32_f16(c1h, blS[ct], accS[1][ct], 0, 0, 0);
      if (DUAL) {
        accT[0][ct] = __builtin_amdgcn_mfma_f32_16x16x32_f16(c0h, bhT[ct], accT[0][ct], 0, 0, 0);
        accT[0][ct] = __builtin_amdgcn_mfma_f32_16x16x32_f16(c0l, bhT[ct], accT[0][ct], 0, 0, 0);
        accT[0][ct] = __builtin_amdgcn_mfma_f32_16x16x32_f16(c0h, blT[ct], accT[0][ct], 0, 0, 0);
        accT[1][ct] = __builtin_amdgcn_mfma_f32_16x16x32_f16(c1h, bhT[ct], accT[1][ct], 0, 0, 0);
        accT[1][ct] = __builtin_amdgcn_mfma_f32_16x16x32_f16(c1l, bhT[ct], accT[1][ct], 0, 0, 0);
        accT[1][ct] = __builtin_amdgcn_mfma_f32_16x16x32_f16(c1h, blT[ct], accT[1][ct], 0, 0, 0);
      }
    }
    c0h = p0h; c1h = p1h; c0l = p0l; c1l = p1l;   // rotate A prefetch
  }

  // epilogue: m = m0 + wr + rt*16 + q*4 + g,  n = n0 + wc + ct*16 + r
#pragma unroll
  for (int rt = 0; rt < 2; ++rt) {
    const int mb = m0 + wr + rt * 16 + q * 4;
#pragma unroll
    for (int ct = 0; ct < 2; ++ct) {
      const int n = n0 + wc + ct * 16 + r;
      if (n >= Nv) continue;
      if (EPI == 2) {
        *(f32x4*)(outT32 + (size_t)n * MM + mb) = accS[rt][ct];
      } else if (EPI == 1) {
#pragma unroll
        for (int g = 0; g < 4; ++g) {
          const int m = mb + g;
          const float v = accS[rt][ct][g];
          const float o = 0.5f * v * (1.0f + ftanh(0.7978845608028654f * (v + 0.044715f * v * v * v)));
          const _Float16 h = (_Float16)o;
          outHi[(size_t)m * ldo + n] = h;
          outLo[(size_t)m * ldo + n] = (_Float16)(o - (float)h);
        }
      } else {
        f32x4 o;
#pragma unroll
        for (int g = 0; g < 4; ++g) {
          const int m = mb + g;
          float v;
          if (VIN16) {
            v = (float)VinHi[(size_t)m * ldv + n] + (float)VinLo[(size_t)m * ldv + n];
          } else {
            v = Vin32[(size_t)m * ldv + n];
          }
          const float s = __expf(ftanh(accS[rt][ct][g]));
          o[g] = v * vscale * s + accT[rt][ct][g];
        }
        if (OUT_T) {
          *(f32x4*)(outT32 + (size_t)n * MM + mb) = o;
        } else {
#pragma unroll
          for (int g = 0; g < 4; ++g) {
            const int m = mb + g;
            const _Float16 h = (_Float16)o[g];
            outHi[(size_t)m * ldo + n] = h;
            outLo[(size_t)m * ldo + n] = (_Float16)(o[g] - (float)h);
          }
        }
      }
    }
  }
}

// ---------------------------------------------------------------------------
// Final elementwise: Pt[840][M] (theta raw | S raw | T), yT[336][M] -> out[B][336][C]
__global__ __launch_bounds__(256) void k_final(const float* __restrict__ Pt,
                                               const float* __restrict__ yT,
                                               const float* __restrict__ Ay,
                                               const float* __restrict__ By,
                                               float* __restrict__ out) {
  const int c = threadIdx.x;                       // 0..63
  const int j = blockIdx.x * 4 + threadIdx.y;      // 0..167
  const int b = blockIdx.y;
  const int m = b * 64 + c;
  const float th = 3.14159265358979323846f * ftanh(Pt[(size_t)j * MM + m]);
  const float sc0 = __expf(ftanh(Pt[(size_t)(168 + 2 * j) * MM + m]));
  const float sc1 = __expf(ftanh(Pt[(size_t)(169 + 2 * j) * MM + m]));
  const float t0 = Pt[(size_t)(504 + 2 * j) * MM + m];
  const float t1 = Pt[(size_t)(505 + 2 * j) * MM + m];
  const float re = yT[(size_t)(2 * j) * MM + m];
  const float im = yT[(size_t)(2 * j + 1) * MM + m];
  const float a = Ay[c * P2C + j], bb = By[c * P2C + j];
  const float rn = rsqrtf(a * a + bb * bb);
  const float ca = a * rn, cb = bb * rn;
  float s1v, c1;
  __sincosf(th, &s1v, &c1);
  const float r1 = c1 * re - s1v * im, i1 = s1v * re + c1 * im;   // rot
  const float r2 = ca * r1 - cb * i1,  i2 = cb * r1 + ca * i1;    // koop
  const float r3 = r2 * sc0,           i3 = i2 * sc1;             // * scale
  const float r4 = ca * r3 + cb * i3,  i4 = ca * i3 - cb * r3;    // koop^-1
  const float r5 = c1 * r4 + s1v * i4, i5 = c1 * i4 - s1v * r4;   // rot^-1
  out[(size_t)b * PP * CC + (size_t)(2 * j) * CC + c]     = r5 + t0;
  out[(size_t)b * PP * CC + (size_t)(2 * j + 1) * CC + c] = i5 + t1;
}

// ---------------------------------------------------------------------------
extern "C" void kernel_launch(void* const* d_in, const int* in_sizes, int n_in,
                              void* d_out, int out_size, void* d_ws, size_t ws_size,
                              hipStream_t stream) {
  const float* x_bsd   = (const float*)d_in[0];
  const float* z0      = (const float*)d_in[1];
  const float* y0      = (const float*)d_in[2];
  const float* W_h     = (const float*)d_in[3];
  const float* W_ssz   = (const float*)d_in[4];
  const float* W_xz_v2 = (const float*)d_in[5];
  const float* W_xz_v3 = (const float*)d_in[6];
  const float* W_xz_v4 = (const float*)d_in[7];
  const float* W_xz_v5 = (const float*)d_in[8];
  const float* W_zx_v0 = (const float*)d_in[9];
  const float* W_zx_v2 = (const float*)d_in[10];
  const float* W_zx_v3 = (const float*)d_in[11];
  // d_in[12] = W_zx_v5: dead (x never read after), skipped
  const float* W_zy_v4 = (const float*)d_in[13];
  const float* W_rot   = (const float*)d_in[14];
  const float* W_koo   = (const float*)d_in[15];
  const float* a_y     = (const float*)d_in[16];
  const float* b_y     = (const float*)d_in[17];
  float* out = (float*)d_out;

  char* p = (char*)d_ws;
  auto alloc = [&](size_t bytes) -> void* {
    void* r = (void*)p; p += (bytes + 255) & ~(size_t)255; return r;
  };
  float*    yT  = (float*)alloc((size_t)PP * MM * 4);
  float*    Pt  = (float*)alloc((size_t)(P2C * 5) * MM * 4);  // 840 rows
  _Float16* xhi = (_Float16*)alloc((size_t)MM * LLP * 2);
  _Float16* xlo = (_Float16*)alloc((size_t)MM * LLP * 2);
  _Float16* zhi = (_Float16*)alloc((size_t)MM * DD * 2);
  _Float16* zlo = (_Float16*)alloc((size_t)MM * DD * 2);
  _Float16* hhi = (_Float16*)alloc((size_t)MM * HH * 2);
  _Float16* hlo = (_Float16*)alloc((size_t)MM * HH * 2);
  auto wpair = [&](size_t elems, _Float16** lo) -> _Float16* {
    _Float16* hi = (_Float16*)alloc(elems * 2);
    *lo = (_Float16*)alloc(elems * 2);
    return hi;
  };
  // Row counts padded so edge-tile DMA reads stay in-bounds.
  _Float16 *tWhL, *tWsszL, *tWxz2L, *tWxz3L, *tWxz4L, *tWxz5L;
  _Float16 *tWzx0L, *tWzx2L, *tWzx3L, *tWzyL, *tWcatL;
  _Float16* tWh   = wpair((size_t)HH * LLP, &tWhL);
  _Float16* tWssz = wpair((size_t)(2*DD) * DD, &tWsszL);
  _Float16* tWxz2 = wpair((size_t)(2*DD) * LLP, &tWxz2L);
  _Float16* tWxz3 = wpair((size_t)(2*DD) * LLP, &tWxz3L);
  _Float16* tWxz4 = wpair((size_t)(2*DD) * LLP, &tWxz4L);
  _Float16* tWxz5 = wpair((size_t)(2*DD) * LLP, &tWxz5L);
  _Float16* tWzx0 = wpair((size_t)1536 * DD, &tWzx0L);
  _Float16* tWzx2 = wpair((size_t)1536 * DD, &tWzx2L);
  _Float16* tWzx3 = wpair((size_t)1536 * DD, &tWzx3L);
  _Float16* tWzy  = wpair((size_t)768 * DD, &tWzyL);
  _Float16* tWcat = wpair((size_t)896 * DD, &tWcatL);   // [840 real][512]

  // ---- weight convert table
  WTab tab;
  int base = 0;
  auto put = [&](int i, const float* src, _Float16* dh, _Float16* dl,
                 int K, int N, int Kpad) {
    const int tN = (N + 15) / 16;
    tab.d[i] = WDesc{src, dh, dl, K, N, Kpad, base, tN};
    base += ((K + 15) / 16) * tN;
  };
  put(0,  W_h,     tWh,   tWhL,   LL, HH,   LLP);
  put(1,  W_ssz,   tWssz, tWsszL, DD, 2*DD, DD);
  put(2,  W_xz_v2, tWxz2, tWxz2L, LL, 2*DD, LLP);
  put(3,  W_xz_v3, tWxz3, tWxz3L, LL, 2*DD, LLP);
  put(4,  W_xz_v4, tWxz4, tWxz4L, LL, 2*DD, LLP);
  put(5,  W_xz_v5, tWxz5, tWxz5L, LL, 2*DD, LLP);
  put(6,  W_zx_v0, tWzx0, tWzx0L, DD, 2*LL, DD);
  put(7,  W_zx_v2, tWzx2, tWzx2L, DD, 2*LL, DD);
  put(8,  W_zx_v3, tWzx3, tWzx3L, DD, 2*LL, DD);
  put(9,  W_zy_v4, tWzy,  tWzyL,  DD, 2*PP, DD);
  put(10, W_rot,   tWcat, tWcatL, DD, P2C,  DD);
  put(11, W_koo,   tWcat + (size_t)P2C * DD, tWcatL + (size_t)P2C * DD, DD, 2*PP, DD);
  const int total_tiles = base;

  k_convert<<<dim3(total_tiles), dim3(256), 0, stream>>>(tab);
  k_xpose<<<dim3(45, 4, 64), dim3(16, 16), 0, stream>>>(x_bsd, xhi, xlo);

  const dim3 blk(256);
  // h = gelu(x @ W_h)
  k_gemm<1, false, false, false><<<dim3(8, 64), blk, 0, stream>>>(
      xhi, xlo, LLP, tWh, tWhL, LLP,
      nullptr, nullptr, nullptr, 0, 0.f, nullptr, hhi, hlo, HH, LLP, HH);
  // z = affine(z0*0.1, h, W_ssz)
  k_gemm<0, true, false, false><<<dim3(8, 64), blk, 0, stream>>>(
      hhi, hlo, HH, tWssz, tWsszL, DD,
      z0, nullptr, nullptr, DD, 0.1f, nullptr, zhi, zlo, DD, DD, DD);
  // x = affine(x, z, W_zx_v0)
  k_gemm<0, true, true, false><<<dim3(12, 64), blk, 0, stream>>>(
      zhi, zlo, DD, tWzx0, tWzx0L, DD,
      nullptr, xhi, xlo, LLP, 1.f, nullptr, xhi, xlo, LLP, DD, LL);
  // z = affine(z, x, W_xz_v2)
  k_gemm<0, true, true, false><<<dim3(8, 64), blk, 0, stream>>>(
      xhi, xlo, LLP, tWxz2, tWxz2L, LLP,
      nullptr, zhi, zlo, DD, 1.f, nullptr, zhi, zlo, DD, LLP, DD);
  // x = affine(x, z, W_zx_v2)
  k_gemm<0, true, true, false><<<dim3(12, 64), blk, 0, stream>>>(
      zhi, zlo, DD, tWzx2, tWzx2L, DD,
      nullptr, xhi, xlo, LLP, 1.f, nullptr, xhi, xlo, LLP, DD, LL);
  // z = affine(z, x, W_xz_v3)
  k_gemm<0, true, true, false><<<dim3(8, 64), blk, 0, stream>>>(
      xhi, xlo, LLP, tWxz3, tWxz3L, LLP,
      nullptr, zhi, zlo, DD, 1.f, nullptr, zhi, zlo, DD, LLP, DD);
  // x = affine(x, z, W_zx_v3)
  k_gemm<0, true, true, false><<<dim3(12, 64), blk, 0, stream>>>(
      zhi, zlo, DD, tWzx3, tWzx3L, DD,
      nullptr, xhi, xlo, LLP, 1.f, nullptr, xhi, xlo, LLP, DD, LL);
  // z = affine(z, x, W_xz_v4)
  k_gemm<0, true, true, false><<<dim3(8, 64), blk, 0, stream>>>(
      xhi, xlo, LLP, tWxz4, tWxz4L, LLP,
      nullptr, zhi, zlo, DD, 1.f, nullptr, zhi, zlo, DD, LLP, DD);
  // yT = affine(y0*0.1, z, W_zy_v4)  [transposed fp32 out]
  k_gemm<0, true, false, true><<<dim3(6, 64), blk, 0, stream>>>(
      zhi, zlo, DD, tWzy, tWzyL, DD,
      y0, nullptr, nullptr, PP, 0.1f, yT, nullptr, nullptr, 0, DD, PP);
  // z = affine(z, x, W_xz_v5)
  k_gemm<0, true, true, false><<<dim3(8, 64), blk, 0, stream>>>(
      xhi, xlo, LLP, tWxz5, tWxz5L, LLP,
      nullptr, zhi, zlo, DD, 1.f, nullptr, zhi, zlo, DD, LLP, DD);
  // Pt = z @ [W_rot | W_koo]  (raw, transposed fp32 out): 840 cols
  k_gemm<2, false, false, true><<<dim3(14, 64), blk, 0, stream>>>(
      zhi, zlo, DD, tWcat, tWcatL, DD,
      nullptr, nullptr, nullptr, 0, 0.f, Pt, nullptr, nullptr, 0, DD, P2C * 5);
  // final elementwise + transposed store
  k_final<<<dim3(42, 64), dim3(64, 4), 0, stream>>>(Pt, yT, a_y, b_y, out);
}

// Round 10
// 490.406 us; speedup vs baseline: 1.1053x; 1.1053x over previous
//
#include <hip/hip_runtime.h>
#include <hip/hip_bf16.h>
#include <math.h>

#define BB  64
#define CC  64
#define LL  720
#define LLP 736           // 720 padded to multiple of 32
#define DD  512
#define PP  336
#define P2C 168
#define HH  512
#define MM  (BB*CC)       // 4096

typedef _Float16 f16x8 __attribute__((ext_vector_type(8)));
typedef float    f32x4 __attribute__((ext_vector_type(4)));

#define GLDS16(g, l) __builtin_amdgcn_global_load_lds( \
    (const __attribute__((address_space(1))) void*)(g), \
    (__attribute__((address_space(3))) void*)(l), 16, 0, 0)

// Fast tanh: one v_exp + v_rcp; inf-safe (|x| large -> e=inf -> 2/inf=0 -> 1).
__device__ __forceinline__ float ftanh(float x) {
  const float ax = fabsf(x);
  const float e  = __expf(2.f * ax);
  const float t  = 1.f - 2.f / (e + 1.f);
  return copysignf(t, x);
}

// ---------------------------------------------------------------------------
// Batched weight convert: fp32 W[K][N] -> fp16 hi/lo planes Wt[N][Kpad]
struct WDesc { const float* src; _Float16* dstHi; _Float16* dstLo;
               int K, N, Kpad, tbase, tilesN; };
struct WTab  { WDesc d[12]; };

__global__ __launch_bounds__(256) void k_convert(WTab tab) {
  __shared__ float tile[16][17];
  const int bid = blockIdx.x;
  int wi = 0;
#pragma unroll
  for (int i = 1; i < 12; ++i) if (bid >= tab.d[i].tbase) wi = i;
  const WDesc d = tab.d[wi];
  const int lt = bid - d.tbase;
  const int tk = lt / d.tilesN, tn = lt % d.tilesN;
  const int k0 = tk * 16, n0 = tn * 16;
  const int tx = threadIdx.x & 15, ty = threadIdx.x >> 4;
  float v = 0.f;
  if (n0 + tx < d.N) v = d.src[(size_t)(k0 + ty) * d.N + n0 + tx];
  tile[ty][tx] = v;
  __syncthreads();
  if (n0 + ty < d.N) {
    const float w = tile[tx][ty];
    const _Float16 h = (_Float16)w;
    const _Float16 l = (_Float16)(w - (float)h);
    const size_t base = (size_t)(n0 + ty) * d.Kpad;
    d.dstHi[base + k0 + tx] = h;
    d.dstLo[base + k0 + tx] = l;
    if (d.Kpad != d.K && k0 + 16 == d.K) {
      d.dstHi[base + d.K + tx] = (_Float16)0.f;
      d.dstLo[base + d.K + tx] = (_Float16)0.f;
    }
  }
}

// ---------------------------------------------------------------------------
// x_bsd [B][L][C] -> x hi/lo [M][736] (pad cols zeroed)
__global__ __launch_bounds__(256) void k_xpose(const float* __restrict__ xbsd,
                                               _Float16* __restrict__ xhi,
                                               _Float16* __restrict__ xlo) {
  __shared__ float tile[16][17];
  const int b = blockIdx.z, l0 = blockIdx.x * 16, c0 = blockIdx.y * 16;
  const int tx = threadIdx.x, ty = threadIdx.y;
  tile[ty][tx] = xbsd[(size_t)b * LL * CC + (size_t)(l0 + ty) * CC + c0 + tx];
  __syncthreads();
  const float v = tile[tx][ty];
  const _Float16 h = (_Float16)v;
  const _Float16 l = (_Float16)(v - (float)h);
  const size_t m = (size_t)b * CC + c0 + ty;
  xhi[m * LLP + l0 + tx] = h;
  xlo[m * LLP + l0 + tx] = l;
  if (l0 == 704) {
    xhi[m * LLP + 720 + tx] = (_Float16)0.f;
    xlo[m * LLP + 720 + tx] = (_Float16)0.f;
  }
}

// ---------------------------------------------------------------------------
// Split-3 MFMA GEMM v13: BM=32, BN=64, BK=32; 256 threads = 4 waves (2x2:
// wave owns 16 rows x 32 cols, dual S+T). v11 skeleton (2-buffer dbuf, ONE
// __syncthreads/K-step, XCD swizzle, ftanh) — best measured 430 µs.
// v13 change: HALF M-TILE -> DOUBLE GRID. v12's counters proved the kernels
// are pure latency-stalled: FETCH at ideal (22 MB), hbm 9%, MfmaUtil 15%,
// VALU 16%, occupancy 14-24% — every pipe idle. The untouched knob across
// all six schedule variants was resident-wave count: grid was 3 blocks/CU.
// BM=32 doubles blocks (x: 1536 = 6/CU; z: 1024 = 4/CU), LDS/block drops to
// 40 KB dual / 24 KB single (4+ fit), VGPR ~60 -> occupancy ceiling ~2x.
// Total MFMA work unchanged; latency cover doubles.
// EPI: 0 = affine (dual s/t; out = Vin*vscale*exp(tanh(S)) + T)
//      1 = gelu  (single; hi/lo out)
//      2 = raw   (single; transposed fp32 out)
template<int EPI, bool DUAL, bool VIN16, bool OUT_T>
__global__ __launch_bounds__(256)
void k_gemm(const _Float16* Ahi, const _Float16* Alo, int lda,
            const _Float16* Whi, const _Float16* Wlo, int ldw,
            const float* Vin32, const _Float16* VinHi,
            const _Float16* VinLo, int ldv, float vscale,
            float* outT32,
            _Float16* outHi, _Float16* outLo, int ldo,
            int Kp, int Nv) {
  constexpr int NB   = DUAL ? 128 : 64;     // B rows staged (S [+T])
  constexpr int ABUF = 32 * 32;             // halves per A plane (32 rows)
  constexpr int BBUF = NB * 32;             // halves per B plane
  constexpr int SBUF = 2 * ABUF + 2 * BBUF; // halves per pipeline buffer
  constexpr int NCH  = 4 + 2 * (NB / 16);   // DMA chunks of 16 rows
  constexpr int NCHW = NCH / 4;             // chunks per wave (dual 5, single 3)
  __shared__ _Float16 smem[2 * SBUF];       // dual 40 KB, single 24 KB

  // XCD-aware bijective swizzle (nwg % 8 == 0 for every grid used here),
  // decoded m-major so each XCD holds a contiguous run of m-panels.
  const int gx  = gridDim.x;
  const int nwg = gx * gridDim.y;
  const int id  = blockIdx.y * gx + blockIdx.x;
  const int nid = (id & 7) * (nwg >> 3) + (id >> 3);
  const int m0 = (nid / gx) * 32;
  const int n0 = (nid % gx) * 64;

  const int tid = threadIdx.x;
  const int w = tid >> 6, lane = tid & 63, q = lane >> 4, r = lane & 15;
  const int wr = (w & 1) * 16, wc = (w >> 1) * 32;
  const int lr = lane >> 2, ls = lane & 3;  // DMA lane decode

  f32x4 accS[2] = {};
  f32x4 accT[2] = {};

  // ---- issue DMA for k-tile kc into pipeline buffer bsel
  auto stage = [&](int kc, int bsel) {
    const int k0 = kc << 5;
    _Float16* sb = smem + bsel * SBUF;
#pragma unroll
    for (int cc = 0; cc < NCHW; ++cc) {
      const int chunk = w * NCHW + cc;
      const _Float16* gsrc;
      _Float16* ldst;
      if (chunk < 2) {                       // A hi (32 rows)
        const int rb = chunk * 16;
        const int R = rb + lr;
        const int ss = ls ^ ((R >> 1) & 3);
        gsrc = Ahi + (size_t)(m0 + R) * lda + k0 + ss * 8;
        ldst = sb + rb * 32;
      } else if (chunk < 4) {                // A lo
        const int rb = (chunk - 2) * 16;
        const int R = rb + lr;
        const int ss = ls ^ ((R >> 1) & 3);
        gsrc = Alo + (size_t)(m0 + R) * lda + k0 + ss * 8;
        ldst = sb + ABUF + rb * 32;
      } else if (chunk < 4 + NB / 16) {      // B hi
        const int rb = (chunk - 4) * 16;
        const int R = rb + lr;
        const int ss = ls ^ ((R >> 1) & 3);
        const int wrow = (R < 64) ? (n0 + R) : (Nv + n0 + (R - 64));
        gsrc = Whi + (size_t)wrow * ldw + k0 + ss * 8;
        ldst = sb + 2 * ABUF + rb * 32;
      } else {                               // B lo
        const int rb = (chunk - 4 - NB / 16) * 16;
        const int R = rb + lr;
        const int ss = ls ^ ((R >> 1) & 3);
        const int wrow = (R < 64) ? (n0 + R) : (Nv + n0 + (R - 64));
        gsrc = Wlo + (size_t)wrow * ldw + k0 + ss * 8;
        ldst = sb + 2 * ABUF + BBUF + rb * 32;
      }
      GLDS16(gsrc, ldst);
    }
  };

  const int nk = Kp >> 5;
  stage(0, 0);
  int cur = 0;
  for (int kc = 0; kc < nk; ++kc) {
    // Drains vmcnt(0): stage(kc) complete; also guarantees every wave has
    // finished reading buf[cur^1] (previous step) before we overwrite it.
    __syncthreads();
    if (kc + 1 < nk) stage(kc + 1, cur ^ 1);   // prefetch overlaps compute
    const _Float16* sb = smem + cur * SBUF;

    const int R = wr + r;                       // this wave's A row (16-row tile)
    const int t = (q ^ ((R >> 1) & 3)) * 8;
    const f16x8 ah = *(const f16x8*)(sb + R * 32 + t);
    const f16x8 al = *(const f16x8*)(sb + ABUF + R * 32 + t);
#pragma unroll
    for (int ct = 0; ct < 2; ++ct) {
      const int RB = wc + ct * 16 + r;
      const int tb = (q ^ ((RB >> 1) & 3)) * 8;
      const f16x8 bh = *(const f16x8*)(sb + 2 * ABUF + RB * 32 + tb);
      const f16x8 bl = *(const f16x8*)(sb + 2 * ABUF + BBUF + RB * 32 + tb);
      accS[ct] = __builtin_amdgcn_mfma_f32_16x16x32_f16(ah, bh, accS[ct], 0, 0, 0);
      accS[ct] = __builtin_amdgcn_mfma_f32_16x16x32_f16(al, bh, accS[ct], 0, 0, 0);
      accS[ct] = __builtin_amdgcn_mfma_f32_16x16x32_f16(ah, bl, accS[ct], 0, 0, 0);
      if (DUAL) {
        const int RT = 64 + RB;
        const int tt = (q ^ ((RT >> 1) & 3)) * 8;
        const f16x8 chh = *(const f16x8*)(sb + 2 * ABUF + RT * 32 + tt);
        const f16x8 cll = *(const f16x8*)(sb + 2 * ABUF + BBUF + RT * 32 + tt);
        accT[ct] = __builtin_amdgcn_mfma_f32_16x16x32_f16(ah, chh, accT[ct], 0, 0, 0);
        accT[ct] = __builtin_amdgcn_mfma_f32_16x16x32_f16(al, chh, accT[ct], 0, 0, 0);
        accT[ct] = __builtin_amdgcn_mfma_f32_16x16x32_f16(ah, cll, accT[ct], 0, 0, 0);
      }
    }
    cur ^= 1;
  }

  // epilogue: m = m0 + wr + q*4 + g,  n = n0 + wc + ct*16 + r
  const int mb = m0 + wr + q * 4;
#pragma unroll
  for (int ct = 0; ct < 2; ++ct) {
    const int n = n0 + wc + ct * 16 + r;
    if (n >= Nv) continue;
    if (EPI == 2) {
      *(f32x4*)(outT32 + (size_t)n * MM + mb) = accS[ct];
    } else if (EPI == 1) {
#pragma unroll
      for (int g = 0; g < 4; ++g) {
        const int m = mb + g;
        const float v = accS[ct][g];
        const float o = 0.5f * v * (1.0f + ftanh(0.7978845608028654f * (v + 0.044715f * v * v * v)));
        const _Float16 h = (_Float16)o;
        outHi[(size_t)m * ldo + n] = h;
        outLo[(size_t)m * ldo + n] = (_Float16)(o - (float)h);
      }
    } else {
      f32x4 o;
#pragma unroll
      for (int g = 0; g < 4; ++g) {
        const int m = mb + g;
        float v;
        if (VIN16) {
          v = (float)VinHi[(size_t)m * ldv + n] + (float)VinLo[(size_t)m * ldv + n];
        } else {
          v = Vin32[(size_t)m * ldv + n];
        }
        const float s = __expf(ftanh(accS[ct][g]));
        o[g] = v * vscale * s + accT[ct][g];
      }
      if (OUT_T) {
        *(f32x4*)(outT32 + (size_t)n * MM + mb) = o;
      } else {
#pragma unroll
        for (int g = 0; g < 4; ++g) {
          const int m = mb + g;
          const _Float16 h = (_Float16)o[g];
          outHi[(size_t)m * ldo + n] = h;
          outLo[(size_t)m * ldo + n] = (_Float16)(o[g] - (float)h);
        }
      }
    }
  }
}

// ---------------------------------------------------------------------------
// Final elementwise: Pt[840][M] (theta raw | S raw | T), yT[336][M] -> out[B][336][C]
__global__ __launch_bounds__(256) void k_final(const float* __restrict__ Pt,
                                               const float* __restrict__ yT,
                                               const float* __restrict__ Ay,
                                               const float* __restrict__ By,
                                               float* __restrict__ out) {
  const int c = threadIdx.x;                       // 0..63
  const int j = blockIdx.x * 4 + threadIdx.y;      // 0..167
  const int b = blockIdx.y;
  const int m = b * 64 + c;
  const float th = 3.14159265358979323846f * ftanh(Pt[(size_t)j * MM + m]);
  const float sc0 = __expf(ftanh(Pt[(size_t)(168 + 2 * j) * MM + m]));
  const float sc1 = __expf(ftanh(Pt[(size_t)(169 + 2 * j) * MM + m]));
  const float t0 = Pt[(size_t)(504 + 2 * j) * MM + m];
  const float t1 = Pt[(size_t)(505 + 2 * j) * MM + m];
  const float re = yT[(size_t)(2 * j) * MM + m];
  const float im = yT[(size_t)(2 * j + 1) * MM + m];
  const float a = Ay[c * P2C + j], bb = By[c * P2C + j];
  const float rn = rsqrtf(a * a + bb * bb);
  const float ca = a * rn, cb = bb * rn;
  float s1v, c1;
  __sincosf(th, &s1v, &c1);
  const float r1 = c1 * re - s1v * im, i1 = s1v * re + c1 * im;   // rot
  const float r2 = ca * r1 - cb * i1,  i2 = cb * r1 + ca * i1;    // koop
  const float r3 = r2 * sc0,           i3 = i2 * sc1;             // * scale
  const float r4 = ca * r3 + cb * i3,  i4 = ca * i3 - cb * r3;    // koop^-1
  const float r5 = c1 * r4 + s1v * i4, i5 = c1 * i4 - s1v * r4;   // rot^-1
  out[(size_t)b * PP * CC + (size_t)(2 * j) * CC + c]     = r5 + t0;
  out[(size_t)b * PP * CC + (size_t)(2 * j + 1) * CC + c] = i5 + t1;
}

// ---------------------------------------------------------------------------
extern "C" void kernel_launch(void* const* d_in, const int* in_sizes, int n_in,
                              void* d_out, int out_size, void* d_ws, size_t ws_size,
                              hipStream_t stream) {
  const float* x_bsd   = (const float*)d_in[0];
  const float* z0      = (const float*)d_in[1];
  const float* y0      = (const float*)d_in[2];
  const float* W_h     = (const float*)d_in[3];
  const float* W_ssz   = (const float*)d_in[4];
  const float* W_xz_v2 = (const float*)d_in[5];
  const float* W_xz_v3 = (const float*)d_in[6];
  const float* W_xz_v4 = (const float*)d_in[7];
  const float* W_xz_v5 = (const float*)d_in[8];
  const float* W_zx_v0 = (const float*)d_in[9];
  const float* W_zx_v2 = (const float*)d_in[10];
  const float* W_zx_v3 = (const float*)d_in[11];
  // d_in[12] = W_zx_v5: dead (x never read after), skipped
  const float* W_zy_v4 = (const float*)d_in[13];
  const float* W_rot   = (const float*)d_in[14];
  const float* W_koo   = (const float*)d_in[15];
  const float* a_y     = (const float*)d_in[16];
  const float* b_y     = (const float*)d_in[17];
  float* out = (float*)d_out;

  char* p = (char*)d_ws;
  auto alloc = [&](size_t bytes) -> void* {
    void* r = (void*)p; p += (bytes + 255) & ~(size_t)255; return r;
  };
  float*    yT  = (float*)alloc((size_t)PP * MM * 4);
  float*    Pt  = (float*)alloc((size_t)(P2C * 5) * MM * 4);  // 840 rows
  _Float16* xhi = (_Float16*)alloc((size_t)MM * LLP * 2);
  _Float16* xlo = (_Float16*)alloc((size_t)MM * LLP * 2);
  _Float16* zhi = (_Float16*)alloc((size_t)MM * DD * 2);
  _Float16* zlo = (_Float16*)alloc((size_t)MM * DD * 2);
  _Float16* hhi = (_Float16*)alloc((size_t)MM * HH * 2);
  _Float16* hlo = (_Float16*)alloc((size_t)MM * HH * 2);
  auto wpair = [&](size_t elems, _Float16** lo) -> _Float16* {
    _Float16* hi = (_Float16*)alloc(elems * 2);
    *lo = (_Float16*)alloc(elems * 2);
    return hi;
  };
  // Row counts padded so edge-tile DMA reads stay in-bounds.
  _Float16 *tWhL, *tWsszL, *tWxz2L, *tWxz3L, *tWxz4L, *tWxz5L;
  _Float16 *tWzx0L, *tWzx2L, *tWzx3L, *tWzyL, *tWcatL;
  _Float16* tWh   = wpair((size_t)HH * LLP, &tWhL);
  _Float16* tWssz = wpair((size_t)(2*DD) * DD, &tWsszL);
  _Float16* tWxz2 = wpair((size_t)(2*DD) * LLP, &tWxz2L);
  _Float16* tWxz3 = wpair((size_t)(2*DD) * LLP, &tWxz3L);
  _Float16* tWxz4 = wpair((size_t)(2*DD) * LLP, &tWxz4L);
  _Float16* tWxz5 = wpair((size_t)(2*DD) * LLP, &tWxz5L);
  _Float16* tWzx0 = wpair((size_t)1536 * DD, &tWzx0L);
  _Float16* tWzx2 = wpair((size_t)1536 * DD, &tWzx2L);
  _Float16* tWzx3 = wpair((size_t)1536 * DD, &tWzx3L);
  _Float16* tWzy  = wpair((size_t)768 * DD, &tWzyL);
  _Float16* tWcat = wpair((size_t)896 * DD, &tWcatL);   // [840 real][512]

  // ---- weight convert table
  WTab tab;
  int base = 0;
  auto put = [&](int i, const float* src, _Float16* dh, _Float16* dl,
                 int K, int N, int Kpad) {
    const int tN = (N + 15) / 16;
    tab.d[i] = WDesc{src, dh, dl, K, N, Kpad, base, tN};
    base += ((K + 15) / 16) * tN;
  };
  put(0,  W_h,     tWh,   tWhL,   LL, HH,   LLP);
  put(1,  W_ssz,   tWssz, tWsszL, DD, 2*DD, DD);
  put(2,  W_xz_v2, tWxz2, tWxz2L, LL, 2*DD, LLP);
  put(3,  W_xz_v3, tWxz3, tWxz3L, LL, 2*DD, LLP);
  put(4,  W_xz_v4, tWxz4, tWxz4L, LL, 2*DD, LLP);
  put(5,  W_xz_v5, tWxz5, tWxz5L, LL, 2*DD, LLP);
  put(6,  W_zx_v0, tWzx0, tWzx0L, DD, 2*LL, DD);
  put(7,  W_zx_v2, tWzx2, tWzx2L, DD, 2*LL, DD);
  put(8,  W_zx_v3, tWzx3, tWzx3L, DD, 2*LL, DD);
  put(9,  W_zy_v4, tWzy,  tWzyL,  DD, 2*PP, DD);
  put(10, W_rot,   tWcat, tWcatL, DD, P2C,  DD);
  put(11, W_koo,   tWcat + (size_t)P2C * DD, tWcatL + (size_t)P2C * DD, DD, 2*PP, DD);
  const int total_tiles = base;

  k_convert<<<dim3(total_tiles), dim3(256), 0, stream>>>(tab);
  k_xpose<<<dim3(45, 4, 64), dim3(16, 16), 0, stream>>>(x_bsd, xhi, xlo);

  const dim3 blk(256);
  // h = gelu(x @ W_h)
  k_gemm<1, false, false, false><<<dim3(8, 128), blk, 0, stream>>>(
      xhi, xlo, LLP, tWh, tWhL, LLP,
      nullptr, nullptr, nullptr, 0, 0.f, nullptr, hhi, hlo, HH, LLP, HH);
  // z = affine(z0*0.1, h, W_ssz)
  k_gemm<0, true, false, false><<<dim3(8, 128), blk, 0, stream>>>(
      hhi, hlo, HH, tWssz, tWsszL, DD,
      z0, nullptr, nullptr, DD, 0.1f, nullptr, zhi, zlo, DD, DD, DD);
  // x = affine(x, z, W_zx_v0)
  k_gemm<0, true, true, false><<<dim3(12, 128), blk, 0, stream>>>(
      zhi, zlo, DD, tWzx0, tWzx0L, DD,
      nullptr, xhi, xlo, LLP, 1.f, nullptr, xhi, xlo, LLP, DD, LL);
  // z = affine(z, x, W_xz_v2)
  k_gemm<0, true, true, false><<<dim3(8, 128), blk, 0, stream>>>(
      xhi, xlo, LLP, tWxz2, tWxz2L, LLP,
      nullptr, zhi, zlo, DD, 1.f, nullptr, zhi, zlo, DD, LLP, DD);
  // x = affine(x, z, W_zx_v2)
  k_gemm<0, true, true, false><<<dim3(12, 128), blk, 0, stream>>>(
      zhi, zlo, DD, tWzx2, tWzx2L, DD,
      nullptr, xhi, xlo, LLP, 1.f, nullptr, xhi, xlo, LLP, DD, LL);
  // z = affine(z, x, W_xz_v3)
  k_gemm<0, true, true, false><<<dim3(8, 128), blk, 0, stream>>>(
      xhi, xlo, LLP, tWxz3, tWxz3L, LLP,
      nullptr, zhi, zlo, DD, 1.f, nullptr, zhi, zlo, DD, LLP, DD);
  // x = affine(x, z, W_zx_v3)
  k_gemm<0, true, true, false><<<dim3(12, 128), blk, 0, stream>>>(
      zhi, zlo, DD, tWzx3, tWzx3L, DD,
      nullptr, xhi, xlo, LLP, 1.f, nullptr, xhi, xlo, LLP, DD, LL);
  // z = affine(z, x, W_xz_v4)
  k_gemm<0, true, true, false><<<dim3(8, 128), blk, 0, stream>>>(
      xhi, xlo, LLP, tWxz4, tWxz4L, LLP,
      nullptr, zhi, zlo, DD, 1.f, nullptr, zhi, zlo, DD, LLP, DD);
  // yT = affine(y0*0.1, z, W_zy_v4)  [transposed fp32 out]
  k_gemm<0, true, false, true><<<dim3(6, 128), blk, 0, stream>>>(
      zhi, zlo, DD, tWzy, tWzyL, DD,
      y0, nullptr, nullptr, PP, 0.1f, yT, nullptr, nullptr, 0, DD, PP);
  // z = affine(z, x, W_xz_v5)
  k_gemm<0, true, true, false><<<dim3(8, 128), blk, 0, stream>>>(
      xhi, xlo, LLP, tWxz5, tWxz5L, LLP,
      nullptr, zhi, zlo, DD, 1.f, nullptr, zhi, zlo, DD, LLP, DD);
  // Pt = z @ [W_rot | W_koo]  (raw, transposed fp32 out): 840 cols
  k_gemm<2, false, false, true><<<dim3(14, 128), blk, 0, stream>>>(
      zhi, zlo, DD, tWcat, tWcatL, DD,
      nullptr, nullptr, nullptr, 0, 0.f, Pt, nullptr, nullptr, 0, DD, P2C * 5);
  // final elementwise + transposed store
  k_final<<<dim3(42, 64), dim3(64, 4), 0, stream>>>(Pt, yT, a_y, b_y, out);
}

// Round 11
// 428.623 us; speedup vs baseline: 1.2646x; 1.1441x over previous
//
#include <hip/hip_runtime.h>
#include <hip/hip_bf16.h>
#include <math.h>

#define BB  64
#define CC  64
#define LL  720
#define LLP 736           // 720 padded to multiple of 32
#define DD  512
#define PP  336
#define P2C 168
#define HH  512
#define MM  (BB*CC)       // 4096

typedef _Float16 f16x8 __attribute__((ext_vector_type(8)));
typedef float    f32x4 __attribute__((ext_vector_type(4)));

#define GLDS16(g, l) __builtin_amdgcn_global_load_lds( \
    (const __attribute__((address_space(1))) void*)(g), \
    (__attribute__((address_space(3))) void*)(l), 16, 0, 0)

// Fast tanh: one v_exp + v_rcp; inf-safe (|x| large -> e=inf -> 2/inf=0 -> 1).
__device__ __forceinline__ float ftanh(float x) {
  const float ax = fabsf(x);
  const float e  = __expf(2.f * ax);
  const float t  = 1.f - 2.f / (e + 1.f);
  return copysignf(t, x);
}

// ---------------------------------------------------------------------------
// Batched weight convert: fp32 W[K][N] -> fp16 hi/lo planes Wt[N][Kpad]
struct WDesc { const float* src; _Float16* dstHi; _Float16* dstLo;
               int K, N, Kpad, tbase, tilesN; };
struct WTab  { WDesc d[12]; };

__global__ __launch_bounds__(256) void k_convert(WTab tab) {
  __shared__ float tile[16][17];
  const int bid = blockIdx.x;
  int wi = 0;
#pragma unroll
  for (int i = 1; i < 12; ++i) if (bid >= tab.d[i].tbase) wi = i;
  const WDesc d = tab.d[wi];
  const int lt = bid - d.tbase;
  const int tk = lt / d.tilesN, tn = lt % d.tilesN;
  const int k0 = tk * 16, n0 = tn * 16;
  const int tx = threadIdx.x & 15, ty = threadIdx.x >> 4;
  float v = 0.f;
  if (n0 + tx < d.N) v = d.src[(size_t)(k0 + ty) * d.N + n0 + tx];
  tile[ty][tx] = v;
  __syncthreads();
  if (n0 + ty < d.N) {
    const float w = tile[tx][ty];
    const _Float16 h = (_Float16)w;
    const _Float16 l = (_Float16)(w - (float)h);
    const size_t base = (size_t)(n0 + ty) * d.Kpad;
    d.dstHi[base + k0 + tx] = h;
    d.dstLo[base + k0 + tx] = l;
    if (d.Kpad != d.K && k0 + 16 == d.K) {
      d.dstHi[base + d.K + tx] = (_Float16)0.f;
      d.dstLo[base + d.K + tx] = (_Float16)0.f;
    }
  }
}

// ---------------------------------------------------------------------------
// x_bsd [B][L][C] -> x hi/lo [M][736] (pad cols zeroed)
__global__ __launch_bounds__(256) void k_xpose(const float* __restrict__ xbsd,
                                               _Float16* __restrict__ xhi,
                                               _Float16* __restrict__ xlo) {
  __shared__ float tile[16][17];
  const int b = blockIdx.z, l0 = blockIdx.x * 16, c0 = blockIdx.y * 16;
  const int tx = threadIdx.x, ty = threadIdx.y;
  tile[ty][tx] = xbsd[(size_t)b * LL * CC + (size_t)(l0 + ty) * CC + c0 + tx];
  __syncthreads();
  const float v = tile[tx][ty];
  const _Float16 h = (_Float16)v;
  const _Float16 l = (_Float16)(v - (float)h);
  const size_t m = (size_t)b * CC + c0 + ty;
  xhi[m * LLP + l0 + tx] = h;
  xlo[m * LLP + l0 + tx] = l;
  if (l0 == 704) {
    xhi[m * LLP + 720 + tx] = (_Float16)0.f;
    xlo[m * LLP + 720 + tx] = (_Float16)0.f;
  }
}

// ---------------------------------------------------------------------------
// Split-3 MFMA GEMM v14: BM=BN=64, BK=32; 256 threads = 4 waves (2x2: wave
// owns 32x32, dual S+T). v11 skeleton UNCHANGED (best measured 430 µs:
// 2-buffer dbuf, ONE __syncthreads/K-step, XCD swizzle, ftanh epilogues).
// v14 change: PER-BLOCK PHASE STAGGER. Elimination matrix (v6/v9/v10/v12/
// v13): dispatch time invariant to schedule, LDS, DMA, FETCH, occupancy —
// per-CU time == sum of per-block serial times even barrier-free. Remaining
// hypothesis: identical-period blocks launched simultaneously phase-lock
// through shared pipes (all waves hit their DMA-wait window together; no
// ready wave ever covers a stall; CU idles ~70% in lockstep). Fix: hash the
// block id into a 0..7 x 512-cycle prologue sleep so co-resident blocks'
// wait/compute windows interleave. Cost <= 1.5 µs tail skew.
// EPI: 0 = affine (dual s/t; out = Vin*vscale*exp(tanh(S)) + T)
//      1 = gelu  (single; hi/lo out)
//      2 = raw   (single; transposed fp32 out)
template<int EPI, bool DUAL, bool VIN16, bool OUT_T>
__global__ __launch_bounds__(256)
void k_gemm(const _Float16* Ahi, const _Float16* Alo, int lda,
            const _Float16* Whi, const _Float16* Wlo, int ldw,
            const float* Vin32, const _Float16* VinHi,
            const _Float16* VinLo, int ldv, float vscale,
            float* outT32,
            _Float16* outHi, _Float16* outLo, int ldo,
            int Kp, int Nv) {
  constexpr int NB   = DUAL ? 128 : 64;     // B rows staged (S [+T])
  constexpr int ABUF = 64 * 32;             // halves per A plane
  constexpr int BBUF = NB * 32;             // halves per B plane
  constexpr int SBUF = 2 * ABUF + 2 * BBUF; // halves per pipeline buffer
  constexpr int NCH  = 8 + 2 * (NB / 16);   // DMA chunks of 16 rows
  constexpr int NCHW = NCH / 4;             // chunks per wave
  __shared__ _Float16 smem[2 * SBUF];       // dual 48 KB, single 32 KB

  // XCD-aware bijective swizzle (nwg % 8 == 0 for every grid used here),
  // decoded m-major so each XCD holds a contiguous run of m-panels.
  const int gx  = gridDim.x;
  const int nwg = gx * gridDim.y;
  const int id  = blockIdx.y * gx + blockIdx.x;
  const int nid = (id & 7) * (nwg >> 3) + (id >> 3);
  const int m0 = (nid / gx) * 64;
  const int n0 = (nid % gx) * 64;

  // ---- convoy de-phasing: pseudo-random 0..7 x ~512-cycle prologue sleep
  {
    const unsigned ph = ((unsigned)nid * 2654435761u) >> 29;   // 0..7
    for (unsigned i = 0; i < ph; ++i) __builtin_amdgcn_s_sleep(8);
  }

  const int tid = threadIdx.x;
  const int w = tid >> 6, lane = tid & 63, q = lane >> 4, r = lane & 15;
  const int wr = (w & 1) * 32, wc = (w >> 1) * 32;
  const int lr = lane >> 2, ls = lane & 3;  // DMA lane decode

  f32x4 accS[2][2] = {};
  f32x4 accT[2][2] = {};

  // ---- issue DMA for k-tile kc into pipeline buffer bsel
  auto stage = [&](int kc, int bsel) {
    const int k0 = kc << 5;
    _Float16* sb = smem + bsel * SBUF;
#pragma unroll
    for (int cc = 0; cc < NCHW; ++cc) {
      const int chunk = w * NCHW + cc;
      const _Float16* gsrc;
      _Float16* ldst;
      if (chunk < 4) {                       // A hi
        const int rb = chunk * 16;
        const int R = rb + lr;
        const int ss = ls ^ ((R >> 1) & 3);
        gsrc = Ahi + (size_t)(m0 + R) * lda + k0 + ss * 8;
        ldst = sb + rb * 32;
      } else if (chunk < 8) {                // A lo
        const int rb = (chunk - 4) * 16;
        const int R = rb + lr;
        const int ss = ls ^ ((R >> 1) & 3);
        gsrc = Alo + (size_t)(m0 + R) * lda + k0 + ss * 8;
        ldst = sb + ABUF + rb * 32;
      } else if (chunk < 8 + NB / 16) {      // B hi
        const int rb = (chunk - 8) * 16;
        const int R = rb + lr;
        const int ss = ls ^ ((R >> 1) & 3);
        const int wrow = (R < 64) ? (n0 + R) : (Nv + n0 + (R - 64));
        gsrc = Whi + (size_t)wrow * ldw + k0 + ss * 8;
        ldst = sb + 2 * ABUF + rb * 32;
      } else {                               // B lo
        const int rb = (chunk - 8 - NB / 16) * 16;
        const int R = rb + lr;
        const int ss = ls ^ ((R >> 1) & 3);
        const int wrow = (R < 64) ? (n0 + R) : (Nv + n0 + (R - 64));
        gsrc = Wlo + (size_t)wrow * ldw + k0 + ss * 8;
        ldst = sb + 2 * ABUF + BBUF + rb * 32;
      }
      GLDS16(gsrc, ldst);
    }
  };

  const int nk = Kp >> 5;
  stage(0, 0);
  int cur = 0;
  for (int kc = 0; kc < nk; ++kc) {
    // Drains vmcnt(0): stage(kc) complete; also guarantees every wave has
    // finished reading buf[cur^1] (previous step) before we overwrite it.
    __syncthreads();
    if (kc + 1 < nk) stage(kc + 1, cur ^ 1);   // prefetch overlaps compute
    const _Float16* sb = smem + cur * SBUF;

    f16x8 ah[2], al[2];
#pragma unroll
    for (int rt = 0; rt < 2; ++rt) {
      const int R = wr + rt * 16 + r;
      const int t = (q ^ ((R >> 1) & 3)) * 8;
      ah[rt] = *(const f16x8*)(sb + R * 32 + t);
      al[rt] = *(const f16x8*)(sb + ABUF + R * 32 + t);
    }
#pragma unroll
    for (int ct = 0; ct < 2; ++ct) {
      const int RB = wc + ct * 16 + r;
      const int tb = (q ^ ((RB >> 1) & 3)) * 8;
      const f16x8 bh = *(const f16x8*)(sb + 2 * ABUF + RB * 32 + tb);
      const f16x8 bl = *(const f16x8*)(sb + 2 * ABUF + BBUF + RB * 32 + tb);
#pragma unroll
      for (int rt = 0; rt < 2; ++rt) {
        accS[rt][ct] = __builtin_amdgcn_mfma_f32_16x16x32_f16(ah[rt], bh, accS[rt][ct], 0, 0, 0);
        accS[rt][ct] = __builtin_amdgcn_mfma_f32_16x16x32_f16(al[rt], bh, accS[rt][ct], 0, 0, 0);
        accS[rt][ct] = __builtin_amdgcn_mfma_f32_16x16x32_f16(ah[rt], bl, accS[rt][ct], 0, 0, 0);
      }
      if (DUAL) {
        const int RT = 64 + RB;
        const int tt = (q ^ ((RT >> 1) & 3)) * 8;
        const f16x8 chh = *(const f16x8*)(sb + 2 * ABUF + RT * 32 + tt);
        const f16x8 cll = *(const f16x8*)(sb + 2 * ABUF + BBUF + RT * 32 + tt);
#pragma unroll
        for (int rt = 0; rt < 2; ++rt) {
          accT[rt][ct] = __builtin_amdgcn_mfma_f32_16x16x32_f16(ah[rt], chh, accT[rt][ct], 0, 0, 0);
          accT[rt][ct] = __builtin_amdgcn_mfma_f32_16x16x32_f16(al[rt], chh, accT[rt][ct], 0, 0, 0);
          accT[rt][ct] = __builtin_amdgcn_mfma_f32_16x16x32_f16(ah[rt], cll, accT[rt][ct], 0, 0, 0);
        }
      }
    }
    cur ^= 1;
  }

  // epilogue: m = m0 + wr + rt*16 + q*4 + g,  n = n0 + wc + ct*16 + r
#pragma unroll
  for (int rt = 0; rt < 2; ++rt) {
    const int mb = m0 + wr + rt * 16 + q * 4;
#pragma unroll
    for (int ct = 0; ct < 2; ++ct) {
      const int n = n0 + wc + ct * 16 + r;
      if (n >= Nv) continue;
      if (EPI == 2) {
        *(f32x4*)(outT32 + (size_t)n * MM + mb) = accS[rt][ct];
      } else if (EPI == 1) {
#pragma unroll
        for (int g = 0; g < 4; ++g) {
          const int m = mb + g;
          const float v = accS[rt][ct][g];
          const float o = 0.5f * v * (1.0f + ftanh(0.7978845608028654f * (v + 0.044715f * v * v * v)));
          const _Float16 h = (_Float16)o;
          outHi[(size_t)m * ldo + n] = h;
          outLo[(size_t)m * ldo + n] = (_Float16)(o - (float)h);
        }
      } else {
        f32x4 o;
#pragma unroll
        for (int g = 0; g < 4; ++g) {
          const int m = mb + g;
          float v;
          if (VIN16) {
            v = (float)VinHi[(size_t)m * ldv + n] + (float)VinLo[(size_t)m * ldv + n];
          } else {
            v = Vin32[(size_t)m * ldv + n];
          }
          const float s = __expf(ftanh(accS[rt][ct][g]));
          o[g] = v * vscale * s + accT[rt][ct][g];
        }
        if (OUT_T) {
          *(f32x4*)(outT32 + (size_t)n * MM + mb) = o;
        } else {
#pragma unroll
          for (int g = 0; g < 4; ++g) {
            const int m = mb + g;
            const _Float16 h = (_Float16)o[g];
            outHi[(size_t)m * ldo + n] = h;
            outLo[(size_t)m * ldo + n] = (_Float16)(o[g] - (float)h);
          }
        }
      }
    }
  }
}

// ---------------------------------------------------------------------------
// Final elementwise: Pt[840][M] (theta raw | S raw | T), yT[336][M] -> out[B][336][C]
__global__ __launch_bounds__(256) void k_final(const float* __restrict__ Pt,
                                               const float* __restrict__ yT,
                                               const float* __restrict__ Ay,
                                               const float* __restrict__ By,
                                               float* __restrict__ out) {
  const int c = threadIdx.x;                       // 0..63
  const int j = blockIdx.x * 4 + threadIdx.y;      // 0..167
  const int b = blockIdx.y;
  const int m = b * 64 + c;
  const float th = 3.14159265358979323846f * ftanh(Pt[(size_t)j * MM + m]);
  const float sc0 = __expf(ftanh(Pt[(size_t)(168 + 2 * j) * MM + m]));
  const float sc1 = __expf(ftanh(Pt[(size_t)(169 + 2 * j) * MM + m]));
  const float t0 = Pt[(size_t)(504 + 2 * j) * MM + m];
  const float t1 = Pt[(size_t)(505 + 2 * j) * MM + m];
  const float re = yT[(size_t)(2 * j) * MM + m];
  const float im = yT[(size_t)(2 * j + 1) * MM + m];
  const float a = Ay[c * P2C + j], bb = By[c * P2C + j];
  const float rn = rsqrtf(a * a + bb * bb);
  const float ca = a * rn, cb = bb * rn;
  float s1v, c1;
  __sincosf(th, &s1v, &c1);
  const float r1 = c1 * re - s1v * im, i1 = s1v * re + c1 * im;   // rot
  const float r2 = ca * r1 - cb * i1,  i2 = cb * r1 + ca * i1;    // koop
  const float r3 = r2 * sc0,           i3 = i2 * sc1;             // * scale
  const float r4 = ca * r3 + cb * i3,  i4 = ca * i3 - cb * r3;    // koop^-1
  const float r5 = c1 * r4 + s1v * i4, i5 = c1 * i4 - s1v * r4;   // rot^-1
  out[(size_t)b * PP * CC + (size_t)(2 * j) * CC + c]     = r5 + t0;
  out[(size_t)b * PP * CC + (size_t)(2 * j + 1) * CC + c] = i5 + t1;
}

// ---------------------------------------------------------------------------
extern "C" void kernel_launch(void* const* d_in, const int* in_sizes, int n_in,
                              void* d_out, int out_size, void* d_ws, size_t ws_size,
                              hipStream_t stream) {
  const float* x_bsd   = (const float*)d_in[0];
  const float* z0      = (const float*)d_in[1];
  const float* y0      = (const float*)d_in[2];
  const float* W_h     = (const float*)d_in[3];
  const float* W_ssz   = (const float*)d_in[4];
  const float* W_xz_v2 = (const float*)d_in[5];
  const float* W_xz_v3 = (const float*)d_in[6];
  const float* W_xz_v4 = (const float*)d_in[7];
  const float* W_xz_v5 = (const float*)d_in[8];
  const float* W_zx_v0 = (const float*)d_in[9];
  const float* W_zx_v2 = (const float*)d_in[10];
  const float* W_zx_v3 = (const float*)d_in[11];
  // d_in[12] = W_zx_v5: dead (x never read after), skipped
  const float* W_zy_v4 = (const float*)d_in[13];
  const float* W_rot   = (const float*)d_in[14];
  const float* W_koo   = (const float*)d_in[15];
  const float* a_y     = (const float*)d_in[16];
  const float* b_y     = (const float*)d_in[17];
  float* out = (float*)d_out;

  char* p = (char*)d_ws;
  auto alloc = [&](size_t bytes) -> void* {
    void* r = (void*)p; p += (bytes + 255) & ~(size_t)255; return r;
  };
  float*    yT  = (float*)alloc((size_t)PP * MM * 4);
  float*    Pt  = (float*)alloc((size_t)(P2C * 5) * MM * 4);  // 840 rows
  _Float16* xhi = (_Float16*)alloc((size_t)MM * LLP * 2);
  _Float16* xlo = (_Float16*)alloc((size_t)MM * LLP * 2);
  _Float16* zhi = (_Float16*)alloc((size_t)MM * DD * 2);
  _Float16* zlo = (_Float16*)alloc((size_t)MM * DD * 2);
  _Float16* hhi = (_Float16*)alloc((size_t)MM * HH * 2);
  _Float16* hlo = (_Float16*)alloc((size_t)MM * HH * 2);
  auto wpair = [&](size_t elems, _Float16** lo) -> _Float16* {
    _Float16* hi = (_Float16*)alloc(elems * 2);
    *lo = (_Float16*)alloc(elems * 2);
    return hi;
  };
  // Row counts padded so edge-tile DMA reads stay in-bounds.
  _Float16 *tWhL, *tWsszL, *tWxz2L, *tWxz3L, *tWxz4L, *tWxz5L;
  _Float16 *tWzx0L, *tWzx2L, *tWzx3L, *tWzyL, *tWcatL;
  _Float16* tWh   = wpair((size_t)HH * LLP, &tWhL);
  _Float16* tWssz = wpair((size_t)(2*DD) * DD, &tWsszL);
  _Float16* tWxz2 = wpair((size_t)(2*DD) * LLP, &tWxz2L);
  _Float16* tWxz3 = wpair((size_t)(2*DD) * LLP, &tWxz3L);
  _Float16* tWxz4 = wpair((size_t)(2*DD) * LLP, &tWxz4L);
  _Float16* tWxz5 = wpair((size_t)(2*DD) * LLP, &tWxz5L);
  _Float16* tWzx0 = wpair((size_t)1536 * DD, &tWzx0L);
  _Float16* tWzx2 = wpair((size_t)1536 * DD, &tWzx2L);
  _Float16* tWzx3 = wpair((size_t)1536 * DD, &tWzx3L);
  _Float16* tWzy  = wpair((size_t)768 * DD, &tWzyL);
  _Float16* tWcat = wpair((size_t)896 * DD, &tWcatL);   // [840 real][512]

  // ---- weight convert table
  WTab tab;
  int base = 0;
  auto put = [&](int i, const float* src, _Float16* dh, _Float16* dl,
                 int K, int N, int Kpad) {
    const int tN = (N + 15) / 16;
    tab.d[i] = WDesc{src, dh, dl, K, N, Kpad, base, tN};
    base += ((K + 15) / 16) * tN;
  };
  put(0,  W_h,     tWh,   tWhL,   LL, HH,   LLP);
  put(1,  W_ssz,   tWssz, tWsszL, DD, 2*DD, DD);
  put(2,  W_xz_v2, tWxz2, tWxz2L, LL, 2*DD, LLP);
  put(3,  W_xz_v3, tWxz3, tWxz3L, LL, 2*DD, LLP);
  put(4,  W_xz_v4, tWxz4, tWxz4L, LL, 2*DD, LLP);
  put(5,  W_xz_v5, tWxz5, tWxz5L, LL, 2*DD, LLP);
  put(6,  W_zx_v0, tWzx0, tWzx0L, DD, 2*LL, DD);
  put(7,  W_zx_v2, tWzx2, tWzx2L, DD, 2*LL, DD);
  put(8,  W_zx_v3, tWzx3, tWzx3L, DD, 2*LL, DD);
  put(9,  W_zy_v4, tWzy,  tWzyL,  DD, 2*PP, DD);
  put(10, W_rot,   tWcat, tWcatL, DD, P2C,  DD);
  put(11, W_koo,   tWcat + (size_t)P2C * DD, tWcatL + (size_t)P2C * DD, DD, 2*PP, DD);
  const int total_tiles = base;

  k_convert<<<dim3(total_tiles), dim3(256), 0, stream>>>(tab);
  k_xpose<<<dim3(45, 4, 64), dim3(16, 16), 0, stream>>>(x_bsd, xhi, xlo);

  const dim3 blk(256);
  // h = gelu(x @ W_h)
  k_gemm<1, false, false, false><<<dim3(8, 64), blk, 0, stream>>>(
      xhi, xlo, LLP, tWh, tWhL, LLP,
      nullptr, nullptr, nullptr, 0, 0.f, nullptr, hhi, hlo, HH, LLP, HH);
  // z = affine(z0*0.1, h, W_ssz)
  k_gemm<0, true, false, false><<<dim3(8, 64), blk, 0, stream>>>(
      hhi, hlo, HH, tWssz, tWsszL, DD,
      z0, nullptr, nullptr, DD, 0.1f, nullptr, zhi, zlo, DD, DD, DD);
  // x = affine(x, z, W_zx_v0)
  k_gemm<0, true, true, false><<<dim3(12, 64), blk, 0, stream>>>(
      zhi, zlo, DD, tWzx0, tWzx0L, DD,
      nullptr, xhi, xlo, LLP, 1.f, nullptr, xhi, xlo, LLP, DD, LL);
  // z = affine(z, x, W_xz_v2)
  k_gemm<0, true, true, false><<<dim3(8, 64), blk, 0, stream>>>(
      xhi, xlo, LLP, tWxz2, tWxz2L, LLP,
      nullptr, zhi, zlo, DD, 1.f, nullptr, zhi, zlo, DD, LLP, DD);
  // x = affine(x, z, W_zx_v2)
  k_gemm<0, true, true, false><<<dim3(12, 64), blk, 0, stream>>>(
      zhi, zlo, DD, tWzx2, tWzx2L, DD,
      nullptr, xhi, xlo, LLP, 1.f, nullptr, xhi, xlo, LLP, DD, LL);
  // z = affine(z, x, W_xz_v3)
  k_gemm<0, true, true, false><<<dim3(8, 64), blk, 0, stream>>>(
      xhi, xlo, LLP, tWxz3, tWxz3L, LLP,
      nullptr, zhi, zlo, DD, 1.f, nullptr, zhi, zlo, DD, LLP, DD);
  // x = affine(x, z, W_zx_v3)
  k_gemm<0, true, true, false><<<dim3(12, 64), blk, 0, stream>>>(
      zhi, zlo, DD, tWzx3, tWzx3L, DD,
      nullptr, xhi, xlo, LLP, 1.f, nullptr, xhi, xlo, LLP, DD, LL);
  // z = affine(z, x, W_xz_v4)
  k_gemm<0, true, true, false><<<dim3(8, 64), blk, 0, stream>>>(
      xhi, xlo, LLP, tWxz4, tWxz4L, LLP,
      nullptr, zhi, zlo, DD, 1.f, nullptr, zhi, zlo, DD, LLP, DD);
  // yT = affine(y0*0.1, z, W_zy_v4)  [transposed fp32 out]
  k_gemm<0, true, false, true><<<dim3(6, 64), blk, 0, stream>>>(
      zhi, zlo, DD, tWzy, tWzyL, DD,
      y0, nullptr, nullptr, PP, 0.1f, yT, nullptr, nullptr, 0, DD, PP);
  // z = affine(z, x, W_xz_v5)
  k_gemm<0, true, true, false><<<dim3(8, 64), blk, 0, stream>>>(
      xhi, xlo, LLP, tWxz5, tWxz5L, LLP,
      nullptr, zhi, zlo, DD, 1.f, nullptr, zhi, zlo, DD, LLP, DD);
  // Pt = z @ [W_rot | W_koo]  (raw, transposed fp32 out): 840 cols
  k_gemm<2, false, false, true><<<dim3(14, 64), blk, 0, stream>>>(
      zhi, zlo, DD, tWcat, tWcatL, DD,
      nullptr, nullptr, nullptr, 0, 0.f, Pt, nullptr, nullptr, 0, DD, P2C * 5);
  // final elementwise + transposed store
  k_final<<<dim3(42, 64), dim3(64, 4), 0, stream>>>(Pt, yT, a_y, b_y, out);
}